// Round 5
// baseline (675.586 us; speedup 1.0000x reference)
//
#include <hip/hip_runtime.h>
#include <math.h>

#define N_M 100000
#define N_J 100000
#define NE  1600000
#define NTOT (3*N_M)          // 300000 buckets (mm | mj | jj)
#define ETOT (3*NE)           // 4800000 edges
#define NB_SCAN 293           // ceil(300000/1024)  (fallback path)
#define DD  64
#define HH  64

// 2-level CSR build: 586 coarse bins x 512 buckets/bin
#define NBIN 586
#define BIN_SHIFT 9           // 512 buckets per bin
#define G1 640                // blocks for bin passes
#define EPB ((ETOT + G1 - 1) / G1)   // 7500 edges per block

__device__ __forceinline__ float lrelu(float a){ return a > 0.f ? a : 0.2f*a; }
__device__ __forceinline__ float wmax(float v){
    #pragma unroll
    for (int o = 32; o; o >>= 1) v = fmaxf(v, __shfl_xor(v, o));
    return v;
}
__device__ __forceinline__ float wsum(float v){
    #pragma unroll
    for (int o = 32; o; o >>= 1) v += __shfl_xor(v, o);
    return v;
}
__device__ __forceinline__ float sigm(float x){ return 1.f/(1.f + expf(-x)); }

// bf16 pack/unpack (RNE)
__device__ __forceinline__ unsigned short f2bf(float f){
    unsigned u = __float_as_uint(f);
    u += 0x7FFFu + ((u >> 16) & 1u);
    return (unsigned short)(u >> 16);
}
__device__ __forceinline__ float bf2f(unsigned short h){
    return __uint_as_float((unsigned)h << 16);
}

// ---------------- dense prep ----------------

__global__ void k_vdst(const float* __restrict__ w_dst, const float* __restrict__ att_dst,
                       float* __restrict__ v_dst){
    int d = threadIdx.x;
    float s = 0.f;
    for (int h = 0; h < HH; ++h) s += w_dst[d*HH + h] * att_dst[h];
    v_dst[d] = s;
}

// hs(bf16) = x @ w_src ; as_ = hs . att_src ; ad_ = x . v_dst
__global__ __launch_bounds__(256) void k_muon_prep(
    const float* __restrict__ x, const float* __restrict__ w_src,
    const float* __restrict__ att_src, const float* __restrict__ v_dst,
    unsigned short* __restrict__ hs_b, float* __restrict__ as_, float* __restrict__ ad_)
{
    __shared__ float lw[DD*HH];
    __shared__ float latt[HH];
    __shared__ float lvd[DD];
    int tid = threadIdx.x;
    for (int i = tid; i < DD*HH; i += 256) lw[i] = w_src[i];
    if (tid < HH) latt[tid] = att_src[tid];
    if (tid < DD) lvd[tid] = v_dst[tid];
    __syncthreads();
    int row = blockIdx.x*64 + (tid >> 2);
    int q = tid & 3;
    if (row >= N_M) return;
    const float4* x4 = (const float4*)(x + (size_t)row*DD);
    float acc[16];
    #pragma unroll
    for (int f = 0; f < 16; ++f) acc[f] = 0.f;
    float adp = 0.f;
    for (int kk = 0; kk < 16; ++kk){
        float4 xv = x4[kk];
        adp += xv.x*lvd[4*kk] + xv.y*lvd[4*kk+1] + xv.z*lvd[4*kk+2] + xv.w*lvd[4*kk+3];
        float xs[4] = {xv.x, xv.y, xv.z, xv.w};
        #pragma unroll
        for (int j = 0; j < 4; ++j){
            const float* wp = lw + (4*kk + j)*HH + (q << 4);
            float xk = xs[j];
            #pragma unroll
            for (int f = 0; f < 16; ++f) acc[f] = fmaf(xk, wp[f], acc[f]);
        }
    }
    float asp = 0.f;
    #pragma unroll
    for (int f = 0; f < 16; ++f) asp += acc[f] * latt[(q<<4) + f];
    asp += __shfl_xor(asp, 1);
    asp += __shfl_xor(asp, 2);
    unsigned short* hp = hs_b + (size_t)row*HH + (q << 4);
    #pragma unroll
    for (int j = 0; j < 4; ++j)
        ((ushort4*)hp)[j] = make_ushort4(f2bf(acc[4*j]), f2bf(acc[4*j+1]),
                                         f2bf(acc[4*j+2]), f2bf(acc[4*j+3]));
    if (q == 0){ as_[row] = asp; ad_[row] = adp; }
}

// xw(bf16) = x_jets @ gcn_w
__global__ __launch_bounds__(256) void k_gcn_xw(
    const float* __restrict__ x, const float* __restrict__ w, unsigned short* __restrict__ xw_b)
{
    __shared__ float lw[DD*HH];
    int tid = threadIdx.x;
    for (int i = tid; i < DD*HH; i += 256) lw[i] = w[i];
    __syncthreads();
    int row = blockIdx.x*64 + (tid >> 2);
    int q = tid & 3;
    if (row >= N_J) return;
    const float4* x4 = (const float4*)(x + (size_t)row*DD);
    float acc[16];
    #pragma unroll
    for (int f = 0; f < 16; ++f) acc[f] = 0.f;
    for (int kk = 0; kk < 16; ++kk){
        float4 xv = x4[kk];
        float xs[4] = {xv.x, xv.y, xv.z, xv.w};
        #pragma unroll
        for (int j = 0; j < 4; ++j){
            const float* wp = lw + (4*kk + j)*HH + (q << 4);
            float xk = xs[j];
            #pragma unroll
            for (int f = 0; f < 16; ++f) acc[f] = fmaf(xk, wp[f], acc[f]);
        }
    }
    unsigned short* hp = xw_b + (size_t)row*HH + (q << 4);
    #pragma unroll
    for (int j = 0; j < 4; ++j)
        ((ushort4*)hp)[j] = make_ushort4(f2bf(acc[4*j]), f2bf(acc[4*j+1]),
                                         f2bf(acc[4*j+2]), f2bf(acc[4*j+3]));
}

// bf16 copy of x_muons for the SAGE gather
__global__ void k_xm(const float* __restrict__ x, unsigned short* __restrict__ xb){
    int i = blockIdx.x*256 + threadIdx.x;
    if (i >= N_M*DD/4) return;
    float4 v = ((const float4*)x)[i];
    ((ushort4*)xb)[i] = make_ushort4(f2bf(v.x), f2bf(v.y), f2bf(v.z), f2bf(v.w));
}

// ---------------- 2-level CSR build ----------------

__device__ __forceinline__ void edge_rd(int t, const int* ei_mm, const int* ei_mj,
                                        const int* ei_jj, const int** ei, int* r, int* e){
    if (t < NE){ *r = 0; *e = t; *ei = ei_mm; }
    else if (t < 2*NE){ *r = 1; *e = t - NE; *ei = ei_mj; }
    else { *r = 2; *e = t - 2*NE; *ei = ei_jj; }
}

__global__ __launch_bounds__(256) void k_bin0(
    const int* __restrict__ ei_mm, const int* __restrict__ ei_mj,
    const int* __restrict__ ei_jj, int* __restrict__ g_bincnt)
{
    __shared__ int bh[NBIN];
    int tid = threadIdx.x;
    for (int i = tid; i < NBIN; i += 256) bh[i] = 0;
    __syncthreads();
    int t0 = blockIdx.x * EPB;
    int t1 = min(t0 + EPB, ETOT);
    for (int t = t0 + tid; t < t1; t += 256){
        const int* ei; int r, e;
        edge_rd(t, ei_mm, ei_mj, ei_jj, &ei, &r, &e);
        int bucket = r*N_M + ei[NE + e];
        atomicAdd(&bh[bucket >> BIN_SHIFT], 1);
    }
    __syncthreads();
    for (int i = tid; i < NBIN; i += 256)
        if (bh[i]) atomicAdd(&g_bincnt[i], bh[i]);
}

__global__ void k_binscan(const int* __restrict__ g_bincnt, int* __restrict__ g_binoff,
                          int* __restrict__ g_bincur, int* __restrict__ offs)
{
    int l = threadIdx.x;            // 0..63
    int base = l * 10;              // 64*10 = 640 >= NBIN
    int v[10]; int s = 0;
    #pragma unroll
    for (int k = 0; k < 10; ++k){
        int idx = base + k;
        v[k] = (idx < NBIN) ? g_bincnt[idx] : 0;
        s += v[k];
    }
    int inc = s;
    #pragma unroll
    for (int o = 1; o < 64; o <<= 1){
        int u = __shfl_up(inc, o);
        if (l >= o) inc += u;
    }
    int ex = inc - s;
    #pragma unroll
    for (int k = 0; k < 10; ++k){
        int idx = base + k;
        if (idx < NBIN){ g_binoff[idx] = ex; g_bincur[idx] = ex; ex += v[k]; }
    }
    if (l == 63) g_binoff[NBIN] = ex;
    if (l == 0)  offs[NTOT] = ETOT;
}

__global__ __launch_bounds__(256) void k_bin1(
    const int* __restrict__ ei_mm, const int* __restrict__ ei_mj,
    const int* __restrict__ ei_jj, int* __restrict__ g_bincur,
    unsigned* __restrict__ binned)
{
    __shared__ int bh[NBIN];
    __shared__ int cb[NBIN];
    int tid = threadIdx.x;
    for (int i = tid; i < NBIN; i += 256) bh[i] = 0;
    __syncthreads();
    int t0 = blockIdx.x * EPB;
    int t1 = min(t0 + EPB, ETOT);
    for (int t = t0 + tid; t < t1; t += 256){
        const int* ei; int r, e;
        edge_rd(t, ei_mm, ei_mj, ei_jj, &ei, &r, &e);
        int bucket = r*N_M + ei[NE + e];
        atomicAdd(&bh[bucket >> BIN_SHIFT], 1);
    }
    __syncthreads();
    for (int i = tid; i < NBIN; i += 256){
        int c = bh[i];
        cb[i] = c ? atomicAdd(&g_bincur[i], c) : 0;
        bh[i] = 0;
    }
    __syncthreads();
    for (int t = t0 + tid; t < t1; t += 256){
        const int* ei; int r, e;
        edge_rd(t, ei_mm, ei_mj, ei_jj, &ei, &r, &e);
        int s = ei[e];
        int bucket = r*N_M + ei[NE + e];
        int bin = bucket >> BIN_SHIFT;
        int lb  = bucket & 511;
        int pos = cb[bin] + atomicAdd(&bh[bin], 1);
        binned[pos] = ((unsigned)lb << 17) | (unsigned)s;
    }
}

__global__ __launch_bounds__(256) void k_build(
    const unsigned* __restrict__ binned, const int* __restrict__ g_binoff,
    int* __restrict__ offs, int* __restrict__ perm)
{
    __shared__ int lh[512];
    __shared__ int lcur[512];
    __shared__ int ls[256];
    int b = blockIdx.x, tid = threadIdx.x;
    int e0 = g_binoff[b], e1 = g_binoff[b+1];
    lh[tid] = 0; lh[tid + 256] = 0;
    __syncthreads();
    for (int e = e0 + tid; e < e1; e += 256)
        atomicAdd(&lh[binned[e] >> 17], 1);
    __syncthreads();
    int a0 = lh[2*tid], a1 = lh[2*tid + 1];
    int s = a0 + a1;
    ls[tid] = s; __syncthreads();
    for (int o = 1; o < 256; o <<= 1){
        int u = (tid >= o) ? ls[tid - o] : 0;
        __syncthreads();
        ls[tid] += u;
        __syncthreads();
    }
    int ex = ls[tid] - s;
    lcur[2*tid]     = ex;
    lcur[2*tid + 1] = ex + a0;
    int gb = b*512 + 2*tid;
    if (gb     < NTOT) offs[gb]     = e0 + ex;
    if (gb + 1 < NTOT) offs[gb + 1] = e0 + ex + a0;
    __syncthreads();
    for (int e = e0 + tid; e < e1; e += 256){
        unsigned p = binned[e];
        int pos = atomicAdd(&lcur[p >> 17], 1);
        perm[e0 + pos] = (int)(p & 0x1FFFFu);
    }
}

// ---------------- fallback CSR build ----------------

__global__ void k_hist(const int* __restrict__ ei_mm, const int* __restrict__ ei_mj,
                       const int* __restrict__ ei_jj, int* __restrict__ cnt){
    int t = blockIdx.x*256 + threadIdx.x;
    if (t >= ETOT) return;
    const int* ei; int r, e;
    edge_rd(t, ei_mm, ei_mj, ei_jj, &ei, &r, &e);
    atomicAdd(&cnt[r*N_M + ei[NE + e]], 1);
}

__global__ __launch_bounds__(256) void k_scan1(const int* __restrict__ cnt,
                                               int* __restrict__ offs, int* __restrict__ bsum){
    __shared__ int ls[256];
    int b = blockIdx.x, t = threadIdx.x;
    int base = b*1024 + t*4;
    int4 c = make_int4(0,0,0,0);
    if (base < NTOT) c = *(const int4*)(cnt + base);
    int s = c.x + c.y + c.z + c.w;
    ls[t] = s; __syncthreads();
    for (int o = 1; o < 256; o <<= 1){
        int a = (t >= o) ? ls[t - o] : 0;
        __syncthreads();
        ls[t] += a;
        __syncthreads();
    }
    int excl = ls[t] - s;
    if (t == 255) bsum[b] = ls[255];
    if (base < NTOT){
        offs[base]   = excl;
        offs[base+1] = excl + c.x;
        offs[base+2] = excl + c.x + c.y;
        offs[base+3] = excl + c.x + c.y + c.z;
    }
}

__global__ __launch_bounds__(512) void k_scan2(int* __restrict__ bsum){
    __shared__ int ls[512];
    int t = threadIdx.x;
    int v = (t < NB_SCAN) ? bsum[t] : 0;
    ls[t] = v; __syncthreads();
    for (int o = 1; o < 512; o <<= 1){
        int a = (t >= o) ? ls[t - o] : 0;
        __syncthreads();
        ls[t] += a;
        __syncthreads();
    }
    if (t < NB_SCAN) bsum[t] = ls[t] - v;
}

__global__ void k_scan3(int* __restrict__ offs, const int* __restrict__ bsum){
    int b = blockIdx.x, t = threadIdx.x;
    int base = b*1024 + t*4;
    if (base >= NTOT) return;
    int add = bsum[b];
    int4* p = (int4*)(offs + base);
    int4 v = *p;
    v.x += add; v.y += add; v.z += add; v.w += add;
    *p = v;
}

__global__ void k_fill(const int* __restrict__ ei_mm, const int* __restrict__ ei_mj,
                       const int* __restrict__ ei_jj, const int* __restrict__ offs,
                       int* __restrict__ cursor, int* __restrict__ perm){
    int t = blockIdx.x*256 + threadIdx.x;
    if (t >= ETOT) return;
    const int* ei; int r, e;
    edge_rd(t, ei_mm, ei_mj, ei_jj, &ei, &r, &e);
    int s = ei[e];
    int bkt = r*N_M + ei[NE + e];
    int pos = atomicAdd(&cursor[bkt], 1);
    perm[offs[bkt] + pos] = s;
}

__global__ void k_set_offs_top(int* __restrict__ offs){ offs[NTOT] = ETOT; }

__global__ void k_dis(const int* __restrict__ offs, float* __restrict__ dis){
    int j = blockIdx.x*256 + threadIdx.x;
    if (j >= N_J) return;
    int beg = offs[2*N_M + j];
    int end = (j == N_J-1) ? ETOT : offs[2*N_M + j + 1];
    dis[j] = rsqrtf((float)(end - beg + 1));
}

// ---------------- fused gather + epilogue (muons + jets in one kernel) ----------------
// even blocks: 8 jets ; odd blocks: 8 muons  (interleaves VALU-heavy and mem-heavy work)

__global__ __launch_bounds__(512) void k_out(
    const float* __restrict__ x_jets, const unsigned short* __restrict__ xm_b,
    const unsigned short* __restrict__ xw_b, const float* __restrict__ dis,
    const int* __restrict__ offs, const int* __restrict__ perm,
    const float* __restrict__ as_, const float* __restrict__ ad_,
    const unsigned short* __restrict__ hs_b, const float* __restrict__ gat_bias,
    const float* __restrict__ w_l, const float* __restrict__ w_r,
    const float* __restrict__ sage_bias, const float* __restrict__ gcn_bias,
    const float* __restrict__ lin_w, const float* __restrict__ lin_b,
    float* __restrict__ out)
{
    __shared__ float lwl[DD*HH];
    __shared__ float lwr[DD*HH];
    int tid = threadIdx.x;
    int wid = tid >> 6;
    int l = tid & 63;
    int b = blockIdx.x;
    if ((b & 1) == 0){
        // ---------------- jets ----------------
        for (int i = tid; i < DD*HH; i += 512){ lwl[i] = w_l[i]; lwr[i] = w_r[i]; }
        __syncthreads();
        int j = (b >> 1)*8 + wid;
        if (j >= N_J) return;
        // SAGE gather (mj relation), bf16 rows
        int beg = offs[N_M + j], end = offs[N_M + j + 1];
        float sa0 = 0.f, sa1 = 0.f;
        for (int base = beg; base < end; base += 64){
            int e = base + l;
            int sB = (e < end) ? perm[e] : 0;
            int cc = min(64, end - base);
            int k = 0;
            for (; k + 8 <= cc; k += 8){
                int s0=__shfl(sB,k+0), s1=__shfl(sB,k+1), s2=__shfl(sB,k+2), s3=__shfl(sB,k+3);
                int s4=__shfl(sB,k+4), s5=__shfl(sB,k+5), s6=__shfl(sB,k+6), s7=__shfl(sB,k+7);
                float v0=bf2f(xm_b[(size_t)s0*DD+l]), v1=bf2f(xm_b[(size_t)s1*DD+l]);
                float v2=bf2f(xm_b[(size_t)s2*DD+l]), v3=bf2f(xm_b[(size_t)s3*DD+l]);
                float v4=bf2f(xm_b[(size_t)s4*DD+l]), v5=bf2f(xm_b[(size_t)s5*DD+l]);
                float v6=bf2f(xm_b[(size_t)s6*DD+l]), v7=bf2f(xm_b[(size_t)s7*DD+l]);
                sa0 += v0 + v2; sa1 += v1 + v3;
                sa0 += v4 + v6; sa1 += v5 + v7;
            }
            for (; k < cc; ++k){
                int sk = __shfl(sB, k);
                sa0 += bf2f(xm_b[(size_t)sk*DD + l]);
            }
        }
        float inv = (end > beg) ? 1.f/(float)(end - beg) : 1.f;
        float mean = (sa0 + sa1) * inv;
        // GCN gather (jj relation), bf16 rows
        int beg2 = offs[2*N_M + j];
        int end2 = (j == N_J-1) ? ETOT : offs[2*N_M + j + 1];
        float dj = dis[j];
        float g0 = dj*dj*bf2f(xw_b[(size_t)j*HH + l]), g1 = 0.f;
        for (int base = beg2; base < end2; base += 64){
            int e = base + l;
            int sB = 0; float nB = 0.f;
            if (e < end2){ sB = perm[e]; nB = dis[sB]*dj; }
            int cc = min(64, end2 - base);
            int k = 0;
            for (; k + 8 <= cc; k += 8){
                int s0=__shfl(sB,k+0), s1=__shfl(sB,k+1), s2=__shfl(sB,k+2), s3=__shfl(sB,k+3);
                int s4=__shfl(sB,k+4), s5=__shfl(sB,k+5), s6=__shfl(sB,k+6), s7=__shfl(sB,k+7);
                float n0=__shfl(nB,k+0), n1=__shfl(nB,k+1), n2=__shfl(nB,k+2), n3=__shfl(nB,k+3);
                float n4=__shfl(nB,k+4), n5=__shfl(nB,k+5), n6=__shfl(nB,k+6), n7=__shfl(nB,k+7);
                float v0=bf2f(xw_b[(size_t)s0*HH+l]), v1=bf2f(xw_b[(size_t)s1*HH+l]);
                float v2=bf2f(xw_b[(size_t)s2*HH+l]), v3=bf2f(xw_b[(size_t)s3*HH+l]);
                float v4=bf2f(xw_b[(size_t)s4*HH+l]), v5=bf2f(xw_b[(size_t)s5*HH+l]);
                float v6=bf2f(xw_b[(size_t)s6*HH+l]), v7=bf2f(xw_b[(size_t)s7*HH+l]);
                g0 = fmaf(n0,v0,g0); g1 = fmaf(n1,v1,g1);
                g0 = fmaf(n2,v2,g0); g1 = fmaf(n3,v3,g1);
                g0 = fmaf(n4,v4,g0); g1 = fmaf(n5,v5,g1);
                g0 = fmaf(n6,v6,g0); g1 = fmaf(n7,v7,g1);
            }
            for (; k < cc; ++k){
                int sk = __shfl(sB, k);
                float nk = __shfl(nB, k);
                g0 = fmaf(nk, bf2f(xw_b[(size_t)sk*HH + l]), g0);
            }
        }
        // mean @ w_l + x_j @ w_r
        float xv = x_jets[(size_t)j*DD + l];
        float accf = g0 + g1 + gcn_bias[l] + sage_bias[l];
        for (int k = 0; k < 64; ++k){
            float mk = __shfl(mean, k);
            float xk = __shfl(xv, k);
            accf = fmaf(mk, lwl[k*64 + l], fmaf(xk, lwr[k*64 + l], accf));
        }
        float val = fmaxf(accf, 0.f);
        float p0 = wsum(val * lin_w[l*2 + 0]);
        float p1 = wsum(val * lin_w[l*2 + 1]);
        if (l == 0){
            size_t o = (size_t)(N_M + j)*2;
            out[o]   = sigm(p0 + lin_b[0]);
            out[o+1] = sigm(p1 + lin_b[1]);
        }
    } else {
        // ---------------- muons (GAT) ----------------
        int d = (b >> 1)*8 + wid;
        if (d >= N_M) return;
        int beg = offs[d], end = offs[d+1];
        float ad_d = ad_[d];
        float a_self = lrelu(as_[d] + ad_d);
        float am = a_self;
        for (int base = beg; base < end; base += 64){
            int e = base + l;
            if (e < end) am = fmaxf(am, lrelu(as_[perm[e]] + ad_d));
        }
        float m = wmax(am);
        float eself = expf(a_self - m);
        float z = eself;
        float acc0 = eself * bf2f(hs_b[(size_t)d*HH + l]), acc1 = 0.f;
        for (int base = beg; base < end; base += 64){
            int e = base + l;
            int sB = 0; float eaB = 0.f;
            if (e < end){
                sB = perm[e];
                eaB = expf(lrelu(as_[sB] + ad_d) - m);
            }
            z += wsum(eaB);
            int cc = min(64, end - base);
            int k = 0;
            for (; k + 8 <= cc; k += 8){
                int s0=__shfl(sB,k+0), s1=__shfl(sB,k+1), s2=__shfl(sB,k+2), s3=__shfl(sB,k+3);
                int s4=__shfl(sB,k+4), s5=__shfl(sB,k+5), s6=__shfl(sB,k+6), s7=__shfl(sB,k+7);
                float e0=__shfl(eaB,k+0), e1=__shfl(eaB,k+1), e2=__shfl(eaB,k+2), e3=__shfl(eaB,k+3);
                float e4=__shfl(eaB,k+4), e5=__shfl(eaB,k+5), e6=__shfl(eaB,k+6), e7=__shfl(eaB,k+7);
                float v0=bf2f(hs_b[(size_t)s0*HH+l]), v1=bf2f(hs_b[(size_t)s1*HH+l]);
                float v2=bf2f(hs_b[(size_t)s2*HH+l]), v3=bf2f(hs_b[(size_t)s3*HH+l]);
                float v4=bf2f(hs_b[(size_t)s4*HH+l]), v5=bf2f(hs_b[(size_t)s5*HH+l]);
                float v6=bf2f(hs_b[(size_t)s6*HH+l]), v7=bf2f(hs_b[(size_t)s7*HH+l]);
                acc0 = fmaf(e0,v0,acc0); acc1 = fmaf(e1,v1,acc1);
                acc0 = fmaf(e2,v2,acc0); acc1 = fmaf(e3,v3,acc1);
                acc0 = fmaf(e4,v4,acc0); acc1 = fmaf(e5,v5,acc1);
                acc0 = fmaf(e6,v6,acc0); acc1 = fmaf(e7,v7,acc1);
            }
            for (; k < cc; ++k){
                int sk = __shfl(sB, k);
                float eak = __shfl(eaB, k);
                acc0 = fmaf(eak, bf2f(hs_b[(size_t)sk*HH + l]), acc0);
            }
        }
        float val = fmaxf((acc0 + acc1) / z + gat_bias[l], 0.f);
        float p0 = wsum(val * lin_w[l*2 + 0]);
        float p1 = wsum(val * lin_w[l*2 + 1]);
        if (l == 0){
            size_t o = (size_t)d*2;
            out[o]   = sigm(p0 + lin_b[0]);
            out[o+1] = sigm(p1 + lin_b[1]);
        }
    }
}

extern "C" void kernel_launch(void* const* d_in, const int* in_sizes, int n_in,
                              void* d_out, int out_size, void* d_ws, size_t ws_size,
                              hipStream_t stream) {
    const float* x_muons   = (const float*)d_in[0];
    const float* x_jets    = (const float*)d_in[1];
    const int*   ei_mm     = (const int*)d_in[2];
    const int*   ei_mj     = (const int*)d_in[3];
    const int*   ei_jj     = (const int*)d_in[4];
    const float* gat_w_src = (const float*)d_in[5];
    const float* gat_w_dst = (const float*)d_in[6];
    const float* gat_att_s = (const float*)d_in[7];
    const float* gat_att_d = (const float*)d_in[8];
    const float* gat_bias  = (const float*)d_in[9];
    const float* sage_w_l  = (const float*)d_in[10];
    const float* sage_w_r  = (const float*)d_in[11];
    const float* sage_bias = (const float*)d_in[12];
    const float* gcn_w     = (const float*)d_in[13];
    const float* gcn_bias  = (const float*)d_in[14];
    const float* lin_w     = (const float*)d_in[15];
    const float* lin_b     = (const float*)d_in[16];
    float* out = (float*)d_out;

    float* ws = (float*)d_ws;
    size_t o = 0;
    unsigned short* hs_b = (unsigned short*)(ws + o); o += (size_t)N_M*HH/2;   // bf16
    unsigned short* xw_b = (unsigned short*)(ws + o); o += (size_t)N_J*HH/2;   // bf16
    unsigned short* xm_b = (unsigned short*)(ws + o); o += (size_t)N_M*DD/2;   // bf16
    float* as_   = ws + o; o += N_M;
    float* ad_   = ws + o; o += N_M;
    float* dis   = ws + o; o += N_J;
    float* v_dst = ws + o; o += 64;
    int* offs   = (int*)(ws + o); o += NTOT + 4;
    int* perm   = (int*)(ws + o); o += ETOT;
    size_t o_common = o;

    int nb64_m = (N_M + 63) / 64;
    int nb64_j = (N_J + 63) / 64;

    k_vdst<<<1, 64, 0, stream>>>(gat_w_dst, gat_att_d, v_dst);
    k_muon_prep<<<nb64_m, 256, 0, stream>>>(x_muons, gat_w_src, gat_att_s, v_dst, hs_b, as_, ad_);
    k_gcn_xw<<<nb64_j, 256, 0, stream>>>(x_jets, gcn_w, xw_b);
    k_xm<<<(N_M*DD/4 + 255)/256, 256, 0, stream>>>(x_muons, xm_b);

    size_t need_fast = (o_common + ETOT + 3*NBIN + 16) * sizeof(float);
    if (ws_size >= need_fast){
        unsigned* binned = (unsigned*)(ws + o); o += ETOT;
        int* g_bincnt    = (int*)(ws + o); o += NBIN;
        int* g_binoff    = (int*)(ws + o); o += NBIN + 4;
        int* g_bincur    = (int*)(ws + o); o += NBIN;
        hipMemsetAsync(g_bincnt, 0, NBIN*sizeof(int), stream);
        k_bin0<<<G1, 256, 0, stream>>>(ei_mm, ei_mj, ei_jj, g_bincnt);
        k_binscan<<<1, 64, 0, stream>>>(g_bincnt, g_binoff, g_bincur, offs);
        k_bin1<<<G1, 256, 0, stream>>>(ei_mm, ei_mj, ei_jj, g_bincur, binned);
        k_build<<<NBIN, 256, 0, stream>>>(binned, g_binoff, offs, perm);
    } else {
        int* cnt    = (int*)(ws + o); o += NTOT;
        int* cursor = (int*)(ws + o); o += NTOT;
        int* bsum   = (int*)(ws + o); o += 512;
        hipMemsetAsync(cnt,    0, (size_t)NTOT*sizeof(int), stream);
        hipMemsetAsync(cursor, 0, (size_t)NTOT*sizeof(int), stream);
        int nbE3 = (ETOT + 255) / 256;
        k_hist<<<nbE3, 256, 0, stream>>>(ei_mm, ei_mj, ei_jj, cnt);
        k_scan1<<<NB_SCAN, 256, 0, stream>>>(cnt, offs, bsum);
        k_scan2<<<1, 512, 0, stream>>>(bsum);
        k_scan3<<<NB_SCAN, 256, 0, stream>>>(offs, bsum);
        k_fill<<<nbE3, 256, 0, stream>>>(ei_mm, ei_mj, ei_jj, offs, cursor, perm);
        k_set_offs_top<<<1, 1, 0, stream>>>(offs);
    }

    k_dis<<<(N_J + 255)/256, 256, 0, stream>>>(offs, dis);

    // fused output kernel: even blocks jets (8/blk), odd blocks muons (8/blk)
    int nb_out = 2 * ((N_M + 7)/8);   // N_M == N_J
    k_out<<<nb_out, 512, 0, stream>>>(x_jets, xm_b, xw_b, dis, offs, perm,
                                      as_, ad_, hs_b, gat_bias,
                                      sage_w_l, sage_w_r, sage_bias, gcn_bias,
                                      lin_w, lin_b, out);
}

// Round 6
// 421.972 us; speedup vs baseline: 1.6010x; 1.6010x over previous
//
#include <hip/hip_runtime.h>
#include <math.h>

#define N_M 100000
#define N_J 100000
#define NE  1600000
#define NTOT (3*N_M)          // 300000 buckets (mm | mj | jj)
#define ETOT (3*NE)           // 4800000 edges
#define NB_SCAN 293           // ceil(300000/1024)  (fallback path)
#define DD  64
#define HH  64

// 2-level CSR build: 586 coarse bins x 512 buckets/bin
#define NBIN 586
#define BIN_SHIFT 9
#define G1 640
#define EPB ((ETOT + G1 - 1) / G1)

__device__ __forceinline__ float lrelu(float a){ return a > 0.f ? a : 0.2f*a; }
__device__ __forceinline__ float wmax(float v){
    #pragma unroll
    for (int o = 32; o; o >>= 1) v = fmaxf(v, __shfl_xor(v, o));
    return v;
}
__device__ __forceinline__ float wsum(float v){
    #pragma unroll
    for (int o = 32; o; o >>= 1) v += __shfl_xor(v, o);
    return v;
}
__device__ __forceinline__ float sigm(float x){ return 1.f/(1.f + expf(-x)); }

__device__ __forceinline__ unsigned short f2bf(float f){
    unsigned u = __float_as_uint(f);
    u += 0x7FFFu + ((u >> 16) & 1u);
    return (unsigned short)(u >> 16);
}
__device__ __forceinline__ float bf2f(unsigned short h){
    return __uint_as_float((unsigned)h << 16);
}

// ---------------- dense prep ----------------

__global__ void k_vdst(const float* __restrict__ w_dst, const float* __restrict__ att_dst,
                       float* __restrict__ v_dst){
    int d = threadIdx.x;
    float s = 0.f;
    for (int h = 0; h < HH; ++h) s += w_dst[d*HH + h] * att_dst[h];
    v_dst[d] = s;
}

// hs(bf16) = x @ w_src ; as_ = hs . att_src ; ad_ = x . v_dst
__global__ __launch_bounds__(256) void k_muon_prep(
    const float* __restrict__ x, const float* __restrict__ w_src,
    const float* __restrict__ att_src, const float* __restrict__ v_dst,
    unsigned short* __restrict__ hs_b, float* __restrict__ as_, float* __restrict__ ad_)
{
    __shared__ float lw[DD*HH];
    __shared__ float latt[HH];
    __shared__ float lvd[DD];
    int tid = threadIdx.x;
    for (int i = tid; i < DD*HH; i += 256) lw[i] = w_src[i];
    if (tid < HH) latt[tid] = att_src[tid];
    if (tid < DD) lvd[tid] = v_dst[tid];
    __syncthreads();
    int row = blockIdx.x*64 + (tid >> 2);
    int q = tid & 3;
    if (row >= N_M) return;
    const float4* x4 = (const float4*)(x + (size_t)row*DD);
    float acc[16];
    #pragma unroll
    for (int f = 0; f < 16; ++f) acc[f] = 0.f;
    float adp = 0.f;
    for (int kk = 0; kk < 16; ++kk){
        float4 xv = x4[kk];
        adp += xv.x*lvd[4*kk] + xv.y*lvd[4*kk+1] + xv.z*lvd[4*kk+2] + xv.w*lvd[4*kk+3];
        float xs[4] = {xv.x, xv.y, xv.z, xv.w};
        #pragma unroll
        for (int j = 0; j < 4; ++j){
            const float* wp = lw + (4*kk + j)*HH + (q << 4);
            float xk = xs[j];
            #pragma unroll
            for (int f = 0; f < 16; ++f) acc[f] = fmaf(xk, wp[f], acc[f]);
        }
    }
    float asp = 0.f;
    #pragma unroll
    for (int f = 0; f < 16; ++f) asp += acc[f] * latt[(q<<4) + f];
    asp += __shfl_xor(asp, 1);
    asp += __shfl_xor(asp, 2);
    unsigned short* hp = hs_b + (size_t)row*HH + (q << 4);
    #pragma unroll
    for (int j = 0; j < 4; ++j)
        ((ushort4*)hp)[j] = make_ushort4(f2bf(acc[4*j]), f2bf(acc[4*j+1]),
                                         f2bf(acc[4*j+2]), f2bf(acc[4*j+3]));
    if (q == 0){ as_[row] = asp; ad_[row] = adp; }
}

// xw(bf16) = x_jets @ gcn_w
__global__ __launch_bounds__(256) void k_gcn_xw(
    const float* __restrict__ x, const float* __restrict__ w, unsigned short* __restrict__ xw_b)
{
    __shared__ float lw[DD*HH];
    int tid = threadIdx.x;
    for (int i = tid; i < DD*HH; i += 256) lw[i] = w[i];
    __syncthreads();
    int row = blockIdx.x*64 + (tid >> 2);
    int q = tid & 3;
    if (row >= N_J) return;
    const float4* x4 = (const float4*)(x + (size_t)row*DD);
    float acc[16];
    #pragma unroll
    for (int f = 0; f < 16; ++f) acc[f] = 0.f;
    for (int kk = 0; kk < 16; ++kk){
        float4 xv = x4[kk];
        float xs[4] = {xv.x, xv.y, xv.z, xv.w};
        #pragma unroll
        for (int j = 0; j < 4; ++j){
            const float* wp = lw + (4*kk + j)*HH + (q << 4);
            float xk = xs[j];
            #pragma unroll
            for (int f = 0; f < 16; ++f) acc[f] = fmaf(xk, wp[f], acc[f]);
        }
    }
    unsigned short* hp = xw_b + (size_t)row*HH + (q << 4);
    #pragma unroll
    for (int j = 0; j < 4; ++j)
        ((ushort4*)hp)[j] = make_ushort4(f2bf(acc[4*j]), f2bf(acc[4*j+1]),
                                         f2bf(acc[4*j+2]), f2bf(acc[4*j+3]));
}

// xr(f32) = x_jets @ sage_w_r + sage_bias + gcn_bias   (hoisted out of jet gather)
__global__ __launch_bounds__(256) void k_xr(
    const float* __restrict__ x, const float* __restrict__ w_r,
    const float* __restrict__ sb, const float* __restrict__ gb, float* __restrict__ xr)
{
    __shared__ float lw[DD*HH];
    __shared__ float lb[HH];
    int tid = threadIdx.x;
    for (int i = tid; i < DD*HH; i += 256) lw[i] = w_r[i];
    if (tid < HH) lb[tid] = sb[tid] + gb[tid];
    __syncthreads();
    int row = blockIdx.x*64 + (tid >> 2);
    int q = tid & 3;
    if (row >= N_J) return;
    const float4* x4 = (const float4*)(x + (size_t)row*DD);
    float acc[16];
    #pragma unroll
    for (int f = 0; f < 16; ++f) acc[f] = 0.f;
    for (int kk = 0; kk < 16; ++kk){
        float4 xv = x4[kk];
        float xs[4] = {xv.x, xv.y, xv.z, xv.w};
        #pragma unroll
        for (int j = 0; j < 4; ++j){
            const float* wp = lw + (4*kk + j)*HH + (q << 4);
            float xk = xs[j];
            #pragma unroll
            for (int f = 0; f < 16; ++f) acc[f] = fmaf(xk, wp[f], acc[f]);
        }
    }
    float* hp = xr + (size_t)row*HH + (q << 4);
    #pragma unroll
    for (int j = 0; j < 4; ++j){
        int f0 = (q << 4) + 4*j;
        ((float4*)hp)[j] = make_float4(acc[4*j]   + lb[f0],
                                       acc[4*j+1] + lb[f0+1],
                                       acc[4*j+2] + lb[f0+2],
                                       acc[4*j+3] + lb[f0+3]);
    }
}

// bf16 copy of x_muons for the SAGE gather
__global__ void k_xm(const float* __restrict__ x, unsigned short* __restrict__ xb){
    int i = blockIdx.x*256 + threadIdx.x;
    if (i >= N_M*DD/4) return;
    float4 v = ((const float4*)x)[i];
    ((ushort4*)xb)[i] = make_ushort4(f2bf(v.x), f2bf(v.y), f2bf(v.z), f2bf(v.w));
}

// ---------------- 2-level CSR build ----------------

__device__ __forceinline__ void edge_rd(int t, const int* ei_mm, const int* ei_mj,
                                        const int* ei_jj, const int** ei, int* r, int* e){
    if (t < NE){ *r = 0; *e = t; *ei = ei_mm; }
    else if (t < 2*NE){ *r = 1; *e = t - NE; *ei = ei_mj; }
    else { *r = 2; *e = t - 2*NE; *ei = ei_jj; }
}

__global__ __launch_bounds__(256) void k_bin0(
    const int* __restrict__ ei_mm, const int* __restrict__ ei_mj,
    const int* __restrict__ ei_jj, int* __restrict__ g_bincnt)
{
    __shared__ int bh[NBIN];
    int tid = threadIdx.x;
    for (int i = tid; i < NBIN; i += 256) bh[i] = 0;
    __syncthreads();
    int t0 = blockIdx.x * EPB;
    int t1 = min(t0 + EPB, ETOT);
    for (int t = t0 + tid; t < t1; t += 256){
        const int* ei; int r, e;
        edge_rd(t, ei_mm, ei_mj, ei_jj, &ei, &r, &e);
        int bucket = r*N_M + ei[NE + e];
        atomicAdd(&bh[bucket >> BIN_SHIFT], 1);
    }
    __syncthreads();
    for (int i = tid; i < NBIN; i += 256)
        if (bh[i]) atomicAdd(&g_bincnt[i], bh[i]);
}

__global__ void k_binscan(const int* __restrict__ g_bincnt, int* __restrict__ g_binoff,
                          int* __restrict__ g_bincur, int* __restrict__ offs)
{
    int l = threadIdx.x;
    int base = l * 10;
    int v[10]; int s = 0;
    #pragma unroll
    for (int k = 0; k < 10; ++k){
        int idx = base + k;
        v[k] = (idx < NBIN) ? g_bincnt[idx] : 0;
        s += v[k];
    }
    int inc = s;
    #pragma unroll
    for (int o = 1; o < 64; o <<= 1){
        int u = __shfl_up(inc, o);
        if (l >= o) inc += u;
    }
    int ex = inc - s;
    #pragma unroll
    for (int k = 0; k < 10; ++k){
        int idx = base + k;
        if (idx < NBIN){ g_binoff[idx] = ex; g_bincur[idx] = ex; ex += v[k]; }
    }
    if (l == 63) g_binoff[NBIN] = ex;
    if (l == 0)  offs[NTOT] = ETOT;
}

__global__ __launch_bounds__(256) void k_bin1(
    const int* __restrict__ ei_mm, const int* __restrict__ ei_mj,
    const int* __restrict__ ei_jj, int* __restrict__ g_bincur,
    unsigned* __restrict__ binned)
{
    __shared__ int bh[NBIN];
    __shared__ int cb[NBIN];
    int tid = threadIdx.x;
    for (int i = tid; i < NBIN; i += 256) bh[i] = 0;
    __syncthreads();
    int t0 = blockIdx.x * EPB;
    int t1 = min(t0 + EPB, ETOT);
    for (int t = t0 + tid; t < t1; t += 256){
        const int* ei; int r, e;
        edge_rd(t, ei_mm, ei_mj, ei_jj, &ei, &r, &e);
        int bucket = r*N_M + ei[NE + e];
        atomicAdd(&bh[bucket >> BIN_SHIFT], 1);
    }
    __syncthreads();
    for (int i = tid; i < NBIN; i += 256){
        int c = bh[i];
        cb[i] = c ? atomicAdd(&g_bincur[i], c) : 0;
        bh[i] = 0;
    }
    __syncthreads();
    for (int t = t0 + tid; t < t1; t += 256){
        const int* ei; int r, e;
        edge_rd(t, ei_mm, ei_mj, ei_jj, &ei, &r, &e);
        int s = ei[e];
        int bucket = r*N_M + ei[NE + e];
        int bin = bucket >> BIN_SHIFT;
        int lb  = bucket & 511;
        int pos = cb[bin] + atomicAdd(&bh[bin], 1);
        binned[pos] = ((unsigned)lb << 17) | (unsigned)s;
    }
}

__global__ __launch_bounds__(256) void k_build(
    const unsigned* __restrict__ binned, const int* __restrict__ g_binoff,
    int* __restrict__ offs, int* __restrict__ perm)
{
    __shared__ int lh[512];
    __shared__ int lcur[512];
    __shared__ int ls[256];
    int b = blockIdx.x, tid = threadIdx.x;
    int e0 = g_binoff[b], e1 = g_binoff[b+1];
    lh[tid] = 0; lh[tid + 256] = 0;
    __syncthreads();
    for (int e = e0 + tid; e < e1; e += 256)
        atomicAdd(&lh[binned[e] >> 17], 1);
    __syncthreads();
    int a0 = lh[2*tid], a1 = lh[2*tid + 1];
    int s = a0 + a1;
    ls[tid] = s; __syncthreads();
    for (int o = 1; o < 256; o <<= 1){
        int u = (tid >= o) ? ls[tid - o] : 0;
        __syncthreads();
        ls[tid] += u;
        __syncthreads();
    }
    int ex = ls[tid] - s;
    lcur[2*tid]     = ex;
    lcur[2*tid + 1] = ex + a0;
    int gb = b*512 + 2*tid;
    if (gb     < NTOT) offs[gb]     = e0 + ex;
    if (gb + 1 < NTOT) offs[gb + 1] = e0 + ex + a0;
    __syncthreads();
    for (int e = e0 + tid; e < e1; e += 256){
        unsigned p = binned[e];
        int pos = atomicAdd(&lcur[p >> 17], 1);
        perm[e0 + pos] = (int)(p & 0x1FFFFu);
    }
}

// ---------------- fallback CSR build ----------------

__global__ void k_hist(const int* __restrict__ ei_mm, const int* __restrict__ ei_mj,
                       const int* __restrict__ ei_jj, int* __restrict__ cnt){
    int t = blockIdx.x*256 + threadIdx.x;
    if (t >= ETOT) return;
    const int* ei; int r, e;
    edge_rd(t, ei_mm, ei_mj, ei_jj, &ei, &r, &e);
    atomicAdd(&cnt[r*N_M + ei[NE + e]], 1);
}

__global__ __launch_bounds__(256) void k_scan1(const int* __restrict__ cnt,
                                               int* __restrict__ offs, int* __restrict__ bsum){
    __shared__ int ls[256];
    int b = blockIdx.x, t = threadIdx.x;
    int base = b*1024 + t*4;
    int4 c = make_int4(0,0,0,0);
    if (base < NTOT) c = *(const int4*)(cnt + base);
    int s = c.x + c.y + c.z + c.w;
    ls[t] = s; __syncthreads();
    for (int o = 1; o < 256; o <<= 1){
        int a = (t >= o) ? ls[t - o] : 0;
        __syncthreads();
        ls[t] += a;
        __syncthreads();
    }
    int excl = ls[t] - s;
    if (t == 255) bsum[b] = ls[255];
    if (base < NTOT){
        offs[base]   = excl;
        offs[base+1] = excl + c.x;
        offs[base+2] = excl + c.x + c.y;
        offs[base+3] = excl + c.x + c.y + c.z;
    }
}

__global__ __launch_bounds__(512) void k_scan2(int* __restrict__ bsum){
    __shared__ int ls[512];
    int t = threadIdx.x;
    int v = (t < NB_SCAN) ? bsum[t] : 0;
    ls[t] = v; __syncthreads();
    for (int o = 1; o < 512; o <<= 1){
        int a = (t >= o) ? ls[t - o] : 0;
        __syncthreads();
        ls[t] += a;
        __syncthreads();
    }
    if (t < NB_SCAN) bsum[t] = ls[t] - v;
}

__global__ void k_scan3(int* __restrict__ offs, const int* __restrict__ bsum){
    int b = blockIdx.x, t = threadIdx.x;
    int base = b*1024 + t*4;
    if (base >= NTOT) return;
    int add = bsum[b];
    int4* p = (int4*)(offs + base);
    int4 v = *p;
    v.x += add; v.y += add; v.z += add; v.w += add;
    *p = v;
}

__global__ void k_fill(const int* __restrict__ ei_mm, const int* __restrict__ ei_mj,
                       const int* __restrict__ ei_jj, const int* __restrict__ offs,
                       int* __restrict__ cursor, int* __restrict__ perm){
    int t = blockIdx.x*256 + threadIdx.x;
    if (t >= ETOT) return;
    const int* ei; int r, e;
    edge_rd(t, ei_mm, ei_mj, ei_jj, &ei, &r, &e);
    int s = ei[e];
    int bkt = r*N_M + ei[NE + e];
    int pos = atomicAdd(&cursor[bkt], 1);
    perm[offs[bkt] + pos] = s;
}

__global__ void k_set_offs_top(int* __restrict__ offs){ offs[NTOT] = ETOT; }

__global__ void k_dis(const int* __restrict__ offs, float* __restrict__ dis){
    int j = blockIdx.x*256 + threadIdx.x;
    if (j >= N_J) return;
    int beg = offs[2*N_M + j];
    int end = (j == N_J-1) ? ETOT : offs[2*N_M + j + 1];
    dis[j] = rsqrtf((float)(end - beg + 1));
}

// ---------------- gather kernels (quad layout: lane = group g (row slot) x pos p) ----
// Each wave-load instruction fetches 4 source rows (16 lanes x ushort4 per row).

// muons: GAT with in-register softmax -> relu -> lin -> sigmoid
__global__ __launch_bounds__(512) void k_muon_gat_out(
    const int* __restrict__ offs, const int* __restrict__ perm,
    const float* __restrict__ as_, const float* __restrict__ ad_,
    const unsigned short* __restrict__ hs_b, const float* __restrict__ gat_bias,
    const float* __restrict__ lin_w, const float* __restrict__ lin_b,
    float* __restrict__ out)
{
    int wid = threadIdx.x >> 6;
    int l = threadIdx.x & 63;
    int d = blockIdx.x*8 + wid;
    if (d >= N_M) return;
    int p = l & 15, g = l >> 4;
    int beg = offs[d], end = offs[d+1];
    float ad_d = ad_[d];
    float a_self = lrelu(as_[d] + ad_d);
    // pass 1: segment max, lane-parallel
    float am = a_self;
    for (int base = beg; base < end; base += 64){
        int e = base + l;
        if (e < end) am = fmaxf(am, lrelu(as_[perm[e]] + ad_d));
    }
    float m = wmax(am);
    float eself = expf(a_self - m);
    float z = eself;
    float acc0 = 0.f, acc1 = 0.f, acc2 = 0.f, acc3 = 0.f;
    for (int base = beg; base < end; base += 64){
        int e = base + l;
        int sB = 0; float eaB = 0.f;
        if (e < end){
            sB = perm[e];
            eaB = expf(lrelu(as_[sB] + ad_d) - m);
        }
        z += wsum(eaB);
        int cc = min(64, end - base);
        int k = 0;
        for (; k + 16 <= cc; k += 16){
            #pragma unroll
            for (int qq = 0; qq < 4; ++qq){
                int idx = k + qq*4 + g;
                int s = __shfl(sB, idx);
                float w = __shfl(eaB, idx);
                ushort4 v = *(const ushort4*)(hs_b + (size_t)s*HH + 4*p);
                acc0 = fmaf(w, bf2f(v.x), acc0);
                acc1 = fmaf(w, bf2f(v.y), acc1);
                acc2 = fmaf(w, bf2f(v.z), acc2);
                acc3 = fmaf(w, bf2f(v.w), acc3);
            }
        }
        for (; k < cc; k += 4){
            int idx = k + g;
            int cl = min(idx, cc - 1);
            int s = __shfl(sB, cl);
            float w = __shfl(eaB, cl);
            if (idx >= cc) w = 0.f;
            ushort4 v = *(const ushort4*)(hs_b + (size_t)s*HH + 4*p);
            acc0 = fmaf(w, bf2f(v.x), acc0);
            acc1 = fmaf(w, bf2f(v.y), acc1);
            acc2 = fmaf(w, bf2f(v.z), acc2);
            acc3 = fmaf(w, bf2f(v.w), acc3);
        }
    }
    // fold 4 row-groups
    acc0 += __shfl_xor(acc0, 16); acc0 += __shfl_xor(acc0, 32);
    acc1 += __shfl_xor(acc1, 16); acc1 += __shfl_xor(acc1, 32);
    acc2 += __shfl_xor(acc2, 16); acc2 += __shfl_xor(acc2, 32);
    acc3 += __shfl_xor(acc3, 16); acc3 += __shfl_xor(acc3, 32);
    // self loop
    ushort4 hv = *(const ushort4*)(hs_b + (size_t)d*HH + 4*p);
    acc0 = fmaf(eself, bf2f(hv.x), acc0);
    acc1 = fmaf(eself, bf2f(hv.y), acc1);
    acc2 = fmaf(eself, bf2f(hv.z), acc2);
    acc3 = fmaf(eself, bf2f(hv.w), acc3);
    float rz = 1.f / z;
    float q0 = 0.f, q1 = 0.f;
    {
        float a[4] = {acc0, acc1, acc2, acc3};
        #pragma unroll
        for (int c = 0; c < 4; ++c){
            int f = 4*p + c;
            float val = fmaxf(a[c]*rz + gat_bias[f], 0.f);
            q0 = fmaf(val, lin_w[f*2 + 0], q0);
            q1 = fmaf(val, lin_w[f*2 + 1], q1);
        }
    }
    #pragma unroll
    for (int o = 1; o <= 8; o <<= 1){ q0 += __shfl_xor(q0, o); q1 += __shfl_xor(q1, o); }
    if (l == 0){
        size_t oo = (size_t)d*2;
        out[oo]   = sigm(q0 + lin_b[0]);
        out[oo+1] = sigm(q1 + lin_b[1]);
    }
}

// jets: SAGE mean + GCN gathers (quad) + mean@w_l (LDS) + precomputed xr -> lin -> sigmoid
__global__ __launch_bounds__(512) void k_jet_out(
    const unsigned short* __restrict__ xm_b, const unsigned short* __restrict__ xw_b,
    const float* __restrict__ xr, const float* __restrict__ dis,
    const int* __restrict__ offs, const int* __restrict__ perm,
    const float* __restrict__ w_l,
    const float* __restrict__ lin_w, const float* __restrict__ lin_b,
    float* __restrict__ out)
{
    __shared__ float lwl[DD*HH];
    int tid = threadIdx.x;
    for (int i = tid; i < DD*HH; i += 512) lwl[i] = w_l[i];
    __syncthreads();
    int wid = tid >> 6;
    int l = tid & 63;
    int j = blockIdx.x*8 + wid;
    if (j >= N_J) return;
    int p = l & 15, g = l >> 4;
    // ---- SAGE gather (mj), weight 1 ----
    int beg = offs[N_M + j], end = offs[N_M + j + 1];
    float sa0 = 0.f, sa1 = 0.f, sa2 = 0.f, sa3 = 0.f;
    for (int base = beg; base < end; base += 64){
        int e = base + l;
        int sB = (e < end) ? perm[e] : 0;
        int cc = min(64, end - base);
        int k = 0;
        for (; k + 16 <= cc; k += 16){
            #pragma unroll
            for (int qq = 0; qq < 4; ++qq){
                int idx = k + qq*4 + g;
                int s = __shfl(sB, idx);
                ushort4 v = *(const ushort4*)(xm_b + (size_t)s*DD + 4*p);
                sa0 += bf2f(v.x); sa1 += bf2f(v.y); sa2 += bf2f(v.z); sa3 += bf2f(v.w);
            }
        }
        for (; k < cc; k += 4){
            int idx = k + g;
            int cl = min(idx, cc - 1);
            int s = __shfl(sB, cl);
            float w = (idx < cc) ? 1.f : 0.f;
            ushort4 v = *(const ushort4*)(xm_b + (size_t)s*DD + 4*p);
            sa0 = fmaf(w, bf2f(v.x), sa0);
            sa1 = fmaf(w, bf2f(v.y), sa1);
            sa2 = fmaf(w, bf2f(v.z), sa2);
            sa3 = fmaf(w, bf2f(v.w), sa3);
        }
    }
    sa0 += __shfl_xor(sa0, 16); sa0 += __shfl_xor(sa0, 32);
    sa1 += __shfl_xor(sa1, 16); sa1 += __shfl_xor(sa1, 32);
    sa2 += __shfl_xor(sa2, 16); sa2 += __shfl_xor(sa2, 32);
    sa3 += __shfl_xor(sa3, 16); sa3 += __shfl_xor(sa3, 32);
    float inv = (end > beg) ? 1.f/(float)(end - beg) : 1.f;
    float mean_a[4] = {sa0*inv, sa1*inv, sa2*inv, sa3*inv};
    // ---- GCN gather (jj), weight dis[s]*dj ----
    int beg2 = offs[2*N_M + j];
    int end2 = (j == N_J-1) ? ETOT : offs[2*N_M + j + 1];
    float dj = dis[j];
    float gc0 = 0.f, gc1 = 0.f, gc2 = 0.f, gc3 = 0.f;
    for (int base = beg2; base < end2; base += 64){
        int e = base + l;
        int sB = 0; float nB = 0.f;
        if (e < end2){ sB = perm[e]; nB = dis[sB]*dj; }
        int cc = min(64, end2 - base);
        int k = 0;
        for (; k + 16 <= cc; k += 16){
            #pragma unroll
            for (int qq = 0; qq < 4; ++qq){
                int idx = k + qq*4 + g;
                int s = __shfl(sB, idx);
                float w = __shfl(nB, idx);
                ushort4 v = *(const ushort4*)(xw_b + (size_t)s*HH + 4*p);
                gc0 = fmaf(w, bf2f(v.x), gc0);
                gc1 = fmaf(w, bf2f(v.y), gc1);
                gc2 = fmaf(w, bf2f(v.z), gc2);
                gc3 = fmaf(w, bf2f(v.w), gc3);
            }
        }
        for (; k < cc; k += 4){
            int idx = k + g;
            int cl = min(idx, cc - 1);
            int s = __shfl(sB, cl);
            float w = __shfl(nB, cl);
            if (idx >= cc) w = 0.f;
            ushort4 v = *(const ushort4*)(xw_b + (size_t)s*HH + 4*p);
            gc0 = fmaf(w, bf2f(v.x), gc0);
            gc1 = fmaf(w, bf2f(v.y), gc1);
            gc2 = fmaf(w, bf2f(v.z), gc2);
            gc3 = fmaf(w, bf2f(v.w), gc3);
        }
    }
    gc0 += __shfl_xor(gc0, 16); gc0 += __shfl_xor(gc0, 32);
    gc1 += __shfl_xor(gc1, 16); gc1 += __shfl_xor(gc1, 32);
    gc2 += __shfl_xor(gc2, 16); gc2 += __shfl_xor(gc2, 32);
    gc3 += __shfl_xor(gc3, 16); gc3 += __shfl_xor(gc3, 32);
    // GCN self loop
    {
        ushort4 sv = *(const ushort4*)(xw_b + (size_t)j*HH + 4*p);
        float djj = dj*dj;
        gc0 = fmaf(djj, bf2f(sv.x), gc0);
        gc1 = fmaf(djj, bf2f(sv.y), gc1);
        gc2 = fmaf(djj, bf2f(sv.z), gc2);
        gc3 = fmaf(djj, bf2f(sv.w), gc3);
    }
    // quad -> linear (feature l): source lane l>>2, component l&3 (all lanes hold totals)
    float b0 = __shfl(gc0, l >> 2), b1 = __shfl(gc1, l >> 2);
    float b2 = __shfl(gc2, l >> 2), b3 = __shfl(gc3, l >> 2);
    int c2 = l & 3;
    float accg_lin = (c2 == 0) ? b0 : ((c2 == 1) ? b1 : ((c2 == 2) ? b2 : b3));
    // ---- mean @ w_l (feature-per-lane, conflict-free LDS) ----
    float xacc = 0.f;
    #pragma unroll
    for (int k = 0; k < 64; ++k){
        float mk = __shfl(mean_a[k & 3], k >> 2);
        xacc = fmaf(mk, lwl[k*64 + l], xacc);
    }
    float val = fmaxf(xacc + accg_lin + xr[(size_t)j*HH + l], 0.f);
    float q0 = wsum(val * lin_w[l*2 + 0]);
    float q1 = wsum(val * lin_w[l*2 + 1]);
    if (l == 0){
        size_t oo = (size_t)(N_M + j)*2;
        out[oo]   = sigm(q0 + lin_b[0]);
        out[oo+1] = sigm(q1 + lin_b[1]);
    }
}

extern "C" void kernel_launch(void* const* d_in, const int* in_sizes, int n_in,
                              void* d_out, int out_size, void* d_ws, size_t ws_size,
                              hipStream_t stream) {
    const float* x_muons   = (const float*)d_in[0];
    const float* x_jets    = (const float*)d_in[1];
    const int*   ei_mm     = (const int*)d_in[2];
    const int*   ei_mj     = (const int*)d_in[3];
    const int*   ei_jj     = (const int*)d_in[4];
    const float* gat_w_src = (const float*)d_in[5];
    const float* gat_w_dst = (const float*)d_in[6];
    const float* gat_att_s = (const float*)d_in[7];
    const float* gat_att_d = (const float*)d_in[8];
    const float* gat_bias  = (const float*)d_in[9];
    const float* sage_w_l  = (const float*)d_in[10];
    const float* sage_w_r  = (const float*)d_in[11];
    const float* sage_bias = (const float*)d_in[12];
    const float* gcn_w     = (const float*)d_in[13];
    const float* gcn_bias  = (const float*)d_in[14];
    const float* lin_w     = (const float*)d_in[15];
    const float* lin_b     = (const float*)d_in[16];
    float* out = (float*)d_out;

    float* ws = (float*)d_ws;
    size_t o = 0;
    unsigned short* hs_b = (unsigned short*)(ws + o); o += (size_t)N_M*HH/2;
    unsigned short* xw_b = (unsigned short*)(ws + o); o += (size_t)N_J*HH/2;
    unsigned short* xm_b = (unsigned short*)(ws + o); o += (size_t)N_M*DD/2;
    float* xr    = ws + o; o += (size_t)N_J*HH;
    float* as_   = ws + o; o += N_M;
    float* ad_   = ws + o; o += N_M;
    float* dis   = ws + o; o += N_J;
    float* v_dst = ws + o; o += 64;
    int* offs   = (int*)(ws + o); o += NTOT + 4;
    int* perm   = (int*)(ws + o); o += ETOT;
    size_t o_common = o;

    int nb64_m = (N_M + 63) / 64;
    int nb64_j = (N_J + 63) / 64;

    k_vdst<<<1, 64, 0, stream>>>(gat_w_dst, gat_att_d, v_dst);
    k_muon_prep<<<nb64_m, 256, 0, stream>>>(x_muons, gat_w_src, gat_att_s, v_dst, hs_b, as_, ad_);
    k_gcn_xw<<<nb64_j, 256, 0, stream>>>(x_jets, gcn_w, xw_b);
    k_xr<<<nb64_j, 256, 0, stream>>>(x_jets, sage_w_r, sage_bias, gcn_bias, xr);
    k_xm<<<(N_M*DD/4 + 255)/256, 256, 0, stream>>>(x_muons, xm_b);

    size_t need_fast = (o_common + ETOT + 3*NBIN + 16) * sizeof(float);
    if (ws_size >= need_fast){
        unsigned* binned = (unsigned*)(ws + o); o += ETOT;
        int* g_bincnt    = (int*)(ws + o); o += NBIN;
        int* g_binoff    = (int*)(ws + o); o += NBIN + 4;
        int* g_bincur    = (int*)(ws + o); o += NBIN;
        hipMemsetAsync(g_bincnt, 0, NBIN*sizeof(int), stream);
        k_bin0<<<G1, 256, 0, stream>>>(ei_mm, ei_mj, ei_jj, g_bincnt);
        k_binscan<<<1, 64, 0, stream>>>(g_bincnt, g_binoff, g_bincur, offs);
        k_bin1<<<G1, 256, 0, stream>>>(ei_mm, ei_mj, ei_jj, g_bincur, binned);
        k_build<<<NBIN, 256, 0, stream>>>(binned, g_binoff, offs, perm);
    } else {
        int* cnt    = (int*)(ws + o); o += NTOT;
        int* cursor = (int*)(ws + o); o += NTOT;
        int* bsum   = (int*)(ws + o); o += 512;
        hipMemsetAsync(cnt,    0, (size_t)NTOT*sizeof(int), stream);
        hipMemsetAsync(cursor, 0, (size_t)NTOT*sizeof(int), stream);
        int nbE3 = (ETOT + 255) / 256;
        k_hist<<<nbE3, 256, 0, stream>>>(ei_mm, ei_mj, ei_jj, cnt);
        k_scan1<<<NB_SCAN, 256, 0, stream>>>(cnt, offs, bsum);
        k_scan2<<<1, 512, 0, stream>>>(bsum);
        k_scan3<<<NB_SCAN, 256, 0, stream>>>(offs, bsum);
        k_fill<<<nbE3, 256, 0, stream>>>(ei_mm, ei_mj, ei_jj, offs, cursor, perm);
        k_set_offs_top<<<1, 1, 0, stream>>>(offs);
    }

    k_dis<<<(N_J + 255)/256, 256, 0, stream>>>(offs, dis);

    k_muon_gat_out<<<(N_M + 7)/8, 512, 0, stream>>>(offs, perm, as_, ad_, hs_b,
                                                    gat_bias, lin_w, lin_b, out);
    k_jet_out<<<(N_J + 7)/8, 512, 0, stream>>>(xm_b, xw_b, xr, dis, offs, perm,
                                               sage_w_l, lin_w, lin_b, out);
}